// Round 7
// baseline (378.610 us; speedup 1.0000x reference)
//
#include <hip/hip_runtime.h>

#define NN 2
#define LL 4096
#define HH 12
#define DD 64
#define HD_ 768
#define M_TOT (NN * LL)   // 8192
#define KVSTRIDE 262144   // elems per (n,h) in pre-permuted K'/V' layouts

typedef __bf16 bf16_t;
typedef _Float16 f16_t;
typedef __bf16 bf16x8 __attribute__((ext_vector_type(8)));
typedef _Float16 f16x2 __attribute__((ext_vector_type(2)));
typedef _Float16 f16x4 __attribute__((ext_vector_type(4)));
typedef _Float16 f16x8 __attribute__((ext_vector_type(8)));
typedef float floatx4 __attribute__((ext_vector_type(4)));
typedef float floatx16 __attribute__((ext_vector_type(16)));

// softmax prescale folded into Q at the QKV GEMM: 1/sqrt(64) * log2(e)
#define QSCALE 0.1803368801111f

__device__ __forceinline__ void async_load16(const void* g, void* l) {
    __builtin_amdgcn_global_load_lds(
        (const __attribute__((address_space(1))) unsigned int*)(g),
        (__attribute__((address_space(3))) unsigned int*)(l),
        16, 0, 0);
}

__device__ __forceinline__ f16x2 pkrtz(float a, float b) {
    return __builtin_bit_cast(f16x2, __builtin_amdgcn_cvt_pkrtz(a, b));
}

// ---------------- fp32 -> bf16 convert (x) ---------------------------------
__global__ void cvt_kernel(const float* __restrict__ src, bf16_t* __restrict__ dst, int n4) {
    int i = blockIdx.x * blockDim.x + threadIdx.x;
    if (i < n4) {
        const float4 v = ((const float4*)src)[i];
        bf16_t* d = dst + (size_t)i * 4;
        d[0] = (bf16_t)v.x; d[1] = (bf16_t)v.y; d[2] = (bf16_t)v.z; d[3] = (bf16_t)v.w;
    }
}

// ------------- fp32 W (K x N) -> bf16 W^T (N x K), LDS tile transpose ------
struct WtArgs { const float* W[4]; bf16_t* Wt[4]; };
__global__ __launch_bounds__(256) void cvt_wt_kernel(WtArgs a) {
    __shared__ bf16_t T[64 * 65];
    const int z = blockIdx.z;
    const int k0 = blockIdx.y * 64, n0 = blockIdx.x * 64;
    const int tid = threadIdx.x;
    {
        const int k = tid >> 2;
        const int nc = (tid & 3) * 16;
        const float* src = a.W[z] + (size_t)(k0 + k) * HD_ + n0 + nc;
        for (int i = 0; i < 4; ++i) {
            float4 v = *(const float4*)(src + i * 4);
            T[(nc + i * 4 + 0) * 65 + k] = (bf16_t)v.x;
            T[(nc + i * 4 + 1) * 65 + k] = (bf16_t)v.y;
            T[(nc + i * 4 + 2) * 65 + k] = (bf16_t)v.z;
            T[(nc + i * 4 + 3) * 65 + k] = (bf16_t)v.w;
        }
    }
    __syncthreads();
    {
        const int n = tid >> 2;
        const int kc = (tid & 3) * 16;
        bf16_t* dst = a.Wt[z] + (size_t)(n0 + n) * HD_ + k0 + kc;
        bf16x8 v0, v1;
        for (int j = 0; j < 8; ++j) { v0[j] = T[n * 65 + kc + j]; v1[j] = T[n * 65 + kc + 8 + j]; }
        *(bf16x8*)dst = v0;
        *(bf16x8*)(dst + 8) = v1;
    }
}

// ---------------- m97-style 128x128 GEMM tile core -------------------------
__device__ __forceinline__ void gemm_tile128(
    const bf16_t* __restrict__ A, const bf16_t* __restrict__ Bt,
    bf16_t* As, bf16_t* Bs, int m0, int n0, floatx4 (&acc)[4][4])
{
    const int tid  = threadIdx.x;
    const int w    = tid >> 6, lane = tid & 63;
    const int quad = lane >> 4, l16 = lane & 15;
    const int wm = w >> 1, wn = w & 1;
    const int rsub = lane >> 3;
    const int csub = (lane & 7) * 8;

    const bf16_t* aBase = A + (size_t)(m0 + w * 32 + rsub) * HD_ + csub;
    const bf16_t* bBase = Bt + (size_t)(n0 + w * 32 + rsub) * HD_ + csub;

    for (int kt = 0; kt < HD_; kt += 64) {
        __syncthreads();
        for (int i = 0; i < 4; ++i) {
            const int ar = w * 32 + i * 8;
            async_load16(aBase + (size_t)i * 8 * HD_ + kt, As + ar * 64 + lane * 8);
            async_load16(bBase + (size_t)i * 8 * HD_ + kt, Bs + ar * 64 + lane * 8);
        }
        __syncthreads();
        for (int ks = 0; ks < 2; ++ks) {
            bf16x8 af[4], bf[4];
            for (int mi = 0; mi < 4; ++mi)
                af[mi] = *(const bf16x8*)&As[(wm * 64 + mi * 16 + l16) * 64 + ks * 32 + quad * 8];
            for (int ni = 0; ni < 4; ++ni)
                bf[ni] = *(const bf16x8*)&Bs[(wn * 64 + ni * 16 + l16) * 64 + ks * 32 + quad * 8];
            for (int mi = 0; mi < 4; ++mi)
                for (int ni = 0; ni < 4; ++ni)
                    acc[mi][ni] = __builtin_amdgcn_mfma_f32_16x16x32_bf16(
                        af[mi], bf[ni], acc[mi][ni], 0, 0, 0);
        }
    }
}

// ---------------- fused QKV projection (z = 0:Q, 1:K, 2:V) -----------------
// Epilogue stages the C-tile in LDS in exact output-chunk order, then copies
// out as contiguous 16B stores.
// K' layout: nh | kvb=l>>5 | s=d>>4 | (l&31)+32*((d>>3)&1) | d&7
// V' layout (kv bits 2<->3 swapped so P needs no lane shuffles):
//   nh | (l>>6)*2+(d>>5) | (l>>4)&3 | (d&31)+32*((l>>2)&1) | (l&3)+4*((l>>3)&1)
struct QKVArgs {
    const bf16_t* Bt[3];
    const float* bias[3];
    void* out[3];
};
__global__ __launch_bounds__(256) void gemm_qkv_kernel(const bf16_t* __restrict__ A, QKVArgs p)
{
    __shared__ __align__(16) bf16_t S[2 * 128 * 64];   // As | Bs, reused as out-stage
    const int z = blockIdx.z;
    const int m0 = blockIdx.y * 128, n0 = blockIdx.x * 128;

    floatx4 acc[4][4] = {};
    gemm_tile128(A, p.Bt[z], S, S + 8192, m0, n0, acc);

    const int tid  = threadIdx.x;
    const int lane = tid & 63;
    const int quad = lane >> 4, l16 = lane & 15;
    const int w    = tid >> 6;
    const int wm = w >> 1, wn = w & 1;
    const float scale = (z == 0) ? QSCALE : 1.0f;
    const float* bias = p.bias[z];

    __syncthreads();   // all waves done reading As/Bs
    for (int ni = 0; ni < 4; ++ni) {
        const int dl = ni * 16 + l16;
        const float bv = bias[n0 + wn * 64 + dl];
        for (int mi = 0; mi < 4; ++mi) {
            for (int r = 0; r < 4; ++r) {
                const int ll = wm * 64 + mi * 16 + quad * 4 + r;
                const float val = (acc[mi][ni][r] + bv) * scale;
                int off;
                if (z == 0)
                    off = ll * 64 + dl;
                else if (z == 1)
                    off = ((ll >> 5) * 4 + (dl >> 4)) * 512
                        + ((ll & 31) + 32 * ((dl >> 3) & 1)) * 8 + (dl & 7);
                else
                    off = (((ll >> 6) * 2 + (dl >> 5)) * 4 + ((ll >> 4) & 3)) * 512
                        + ((dl & 31) + 32 * ((ll >> 2) & 1)) * 8
                        + ((ll & 3) + 4 * ((ll >> 3) & 1));
                if (z == 2) ((f16_t*)S)[wn * 8192 + off] = (f16_t)val;
                else        S[wn * 8192 + off] = (bf16_t)val;
            }
        }
    }
    __syncthreads();

    // copy out: 16 KB per head, fully contiguous in global
    const int ht = tid >> 7, idx = tid & 127;
    const int nn = m0 >> 12, l0 = m0 & 4095;
    const int h = (n0 >> 6) + ht;
    char* dstBase;
    if (z == 0)
        dstBase = (char*)p.out[0] + (((size_t)(nn * HH + h) * LL + l0) * 64) * 2;
    else if (z == 1)
        dstBase = (char*)p.out[1] + ((size_t)(nn * HH + h) * KVSTRIDE + (size_t)(l0 >> 5) * 2048) * 2;
    else
        dstBase = (char*)p.out[2] + ((size_t)(nn * HH + h) * KVSTRIDE + (size_t)(l0 >> 6) * 4096) * 2;
    const bf16_t* srcB = S + ht * 8192;
    for (int c = 0; c < 8; ++c) {
        const int cc = (c + idx) & 7;   // bank-rotated: conflict-minimal b128 reads
        *(bf16x8*)(dstBase + (idx * 64 + cc * 8) * 2) = *(const bf16x8*)(srcB + idx * 64 + cc * 8);
    }
}

// ---------------- output projection (fp32 out) -----------------------------
__global__ __launch_bounds__(256) void gemm_o_kernel(
    const bf16_t* __restrict__ A, const bf16_t* __restrict__ Bt,
    const float* __restrict__ bias, float* __restrict__ Cout)
{
    __shared__ __align__(16) bf16_t As[128 * 64];
    __shared__ __align__(16) bf16_t Bs[128 * 64];
    const int m0 = blockIdx.y * 128, n0 = blockIdx.x * 128;

    floatx4 acc[4][4] = {};
    gemm_tile128(A, Bt, As, Bs, m0, n0, acc);

    const int tid  = threadIdx.x;
    const int lane = tid & 63;
    const int quad = lane >> 4, l16 = lane & 15;
    const int w    = tid >> 6;
    const int wm = w >> 1, wn = w & 1;

    for (int ni = 0; ni < 4; ++ni) {
        const int col = n0 + wn * 64 + ni * 16 + l16;
        const float bv = bias[col];
        for (int mi = 0; mi < 4; ++mi)
            for (int r = 0; r < 4; ++r) {
                const int row = m0 + wm * 64 + mi * 16 + quad * 4 + r;
                Cout[(size_t)row * HD_ + col] = acc[mi][ni][r] + bv;
            }
    }
}

// ---------------- flash attention: in-block kv-split, no P shuffles --------
// q-tile 64, 4 waves: waves {0,1} handle kv[0,2048), waves {2,3} kv[2048,4096).
// S^T = K·Q^T (32x32x16 bf16). With the V' bit-swap, C regs feed the PV
// B-operand directly: pf = pack(exp2(sacc regs)) in order. O^T via
// 32x32x16 f16. Halves combine additively in LDS (rowsums are linear).
__global__ __launch_bounds__(256, 5) void attn_kernel(
    const bf16_t* __restrict__ qg, const bf16_t* __restrict__ kf,
    const f16_t* __restrict__ vf, bf16_t* __restrict__ og)
{
    __shared__ union {
        struct { bf16_t Ks[2 * 8 * 512]; f16_t Vs[2 * 8 * 512]; } s;  // 16+16 KB
        struct { float T[64 * 65]; float rsb[64]; } e;                // 16.9 KB
    } u;

    const int tid = threadIdx.x;
    const int w = tid >> 6, lane = tid & 63;
    const int l32 = lane & 31, hi = lane >> 5;
    const int half = w >> 1, wp = w & 1;
    const int qt0 = blockIdx.x * 64;
    const int nh = blockIdx.y;
    const int nIdx = nh / HH, hIdx = nh % HH;

    // Q B-frags: lane (q=l32, hi) holds Q[qrow][s*16 + hi*8 + j]
    bf16x8 qfrag[4];
    {
        const bf16_t* qp = qg + ((size_t)nh * LL + qt0 + wp * 32 + l32) * DD + hi * 8;
        for (int s = 0; s < 4; ++s) qfrag[s] = *(const bf16x8*)(qp + s * 16);
    }

    // staging: wave stages 4 contiguous K chunks (kvb_local=wp) + 4 V chunks (dblk=wp)
    const bf16_t* ksrc = kf + (size_t)nh * KVSTRIDE + (size_t)(half * 64 + wp) * 2048 + lane * 8;
    const f16_t*  vsrc = vf + (size_t)nh * KVSTRIDE + (size_t)(half * 64 + wp) * 2048 + lane * 8;
    bf16_t* kdst = &u.s.Ks[(half * 8 + wp * 4) * 512 + lane * 8];
    f16_t*  vdst = &u.s.Vs[(half * 8 + wp * 4) * 512 + lane * 8];

    floatx16 oacc[2] = {};
    float rs = 0.f;

    for (int t = 0; t < 32; ++t) {
        __syncthreads();
        for (int c = 0; c < 4; ++c) {
            async_load16(ksrc + c * 512, kdst + c * 512);
            async_load16(vsrc + c * 512, vdst + c * 512);
        }
        ksrc += 4096; vsrc += 4096;
        __syncthreads();

        for (int kvb = 0; kvb < 2; ++kvb) {
            floatx16 sacc = {};
            for (int s = 0; s < 4; ++s) {
                bf16x8 ak = *(const bf16x8*)&u.s.Ks[(half * 8 + kvb * 4 + s) * 512 + lane * 8];
                sacc = __builtin_amdgcn_mfma_f32_32x32x16_bf16(ak, qfrag[s], sacc, 0, 0, 0);
            }
            for (int sub = 0; sub < 2; ++sub) {
                float p[8];
                for (int i = 0; i < 8; ++i) {
                    p[i] = __builtin_amdgcn_exp2f(sacc[sub * 8 + i]);
                    rs += p[i];
                }
                f16x2 ab = pkrtz(p[0], p[1]), cd = pkrtz(p[2], p[3]);
                f16x2 ef = pkrtz(p[4], p[5]), gh = pkrtz(p[6], p[7]);
                f16x4 lo4 = __builtin_shufflevector(ab, cd, 0, 1, 2, 3);
                f16x4 hi4 = __builtin_shufflevector(ef, gh, 0, 1, 2, 3);
                f16x8 pf = __builtin_shufflevector(lo4, hi4, 0, 1, 2, 3, 4, 5, 6, 7);
                const int kstep = kvb * 2 + sub;
                for (int db = 0; db < 2; ++db) {
                    f16x8 av = *(const f16x8*)&u.s.Vs[(half * 8 + db * 4 + kstep) * 512 + lane * 8];
                    oacc[db] = __builtin_amdgcn_mfma_f32_32x32x16_f16(av, pf, oacc[db], 0, 0, 0);
                }
            }
        }
    }

    rs += __shfl_xor(rs, 32);

    // combine halves in LDS: pair A writes, pair B accumulates
    const int q = wp * 32 + l32;
    __syncthreads();
    if (half == 0) {
        for (int db = 0; db < 2; ++db)
            for (int g = 0; g < 4; ++g)
                for (int r = 0; r < 4; ++r)
                    u.e.T[q * 65 + db * 32 + hi * 4 + g * 8 + r] = oacc[db][g * 4 + r];
        if (lane < 32) u.e.rsb[q] = rs;
    }
    __syncthreads();
    if (half == 1) {
        for (int db = 0; db < 2; ++db)
            for (int g = 0; g < 4; ++g)
                for (int r = 0; r < 4; ++r)
                    u.e.T[q * 65 + db * 32 + hi * 4 + g * 8 + r] += oacc[db][g * 4 + r];
        if (lane < 32) u.e.rsb[q] += rs;
    }
    __syncthreads();

    // normalize + coalesced store
    const int qo = tid >> 2, c = tid & 3;
    const float rinv = __builtin_amdgcn_rcpf(u.e.rsb[qo]);
    bf16x8 o0, o1;
    for (int j = 0; j < 8; ++j) {
        o0[j] = (bf16_t)(u.e.T[qo * 65 + c * 16 + j] * rinv);
        o1[j] = (bf16_t)(u.e.T[qo * 65 + c * 16 + 8 + j] * rinv);
    }
    bf16_t* dst = og + ((size_t)nIdx * LL + qt0 + qo) * HD_ + hIdx * 64 + c * 16;
    *(bf16x8*)dst = o0;
    *(bf16x8*)(dst + 8) = o1;
}

extern "C" void kernel_launch(void* const* d_in, const int* in_sizes, int n_in,
                              void* d_out, int out_size, void* d_ws, size_t ws_size,
                              hipStream_t stream) {
    const float* x  = (const float*)d_in[0];
    const float* Wq = (const float*)d_in[1];
    const float* bq = (const float*)d_in[2];
    const float* Wk = (const float*)d_in[3];
    const float* bk = (const float*)d_in[4];
    const float* Wv = (const float*)d_in[5];
    const float* bv = (const float*)d_in[6];
    const float* Wo = (const float*)d_in[7];
    const float* bo = (const float*)d_in[8];

    char* ws = (char*)d_ws;
    const size_t xbytes = (size_t)M_TOT * HD_ * 2;
    const size_t wbytes = (size_t)HD_ * HD_ * 2;

    bf16_t* xb  = (bf16_t*)ws; ws += xbytes;
    bf16_t* wqt = (bf16_t*)ws; ws += wbytes;
    bf16_t* wkt = (bf16_t*)ws; ws += wbytes;
    bf16_t* wvt = (bf16_t*)ws; ws += wbytes;
    bf16_t* wot = (bf16_t*)ws; ws += wbytes;
    bf16_t* qb  = (bf16_t*)ws; ws += xbytes;
    bf16_t* kfb = (bf16_t*)ws; ws += xbytes;
    f16_t*  vfb = (f16_t*)ws;  ws += xbytes;
    bf16_t* ob  = (bf16_t*)ws; ws += xbytes;

    cvt_kernel<<<(M_TOT * HD_ / 4 + 255) / 256, 256, 0, stream>>>(x, xb, M_TOT * HD_ / 4);

    WtArgs wa;
    wa.W[0] = Wq; wa.W[1] = Wk; wa.W[2] = Wv; wa.W[3] = Wo;
    wa.Wt[0] = wqt; wa.Wt[1] = wkt; wa.Wt[2] = wvt; wa.Wt[3] = wot;
    cvt_wt_kernel<<<dim3(12, 12, 4), 256, 0, stream>>>(wa);

    QKVArgs qa;
    qa.Bt[0] = wqt; qa.Bt[1] = wkt; qa.Bt[2] = wvt;
    qa.bias[0] = bq; qa.bias[1] = bk; qa.bias[2] = bv;
    qa.out[0] = qb; qa.out[1] = kfb; qa.out[2] = vfb;
    gemm_qkv_kernel<<<dim3(HD_ / 128, M_TOT / 128, 3), 256, 0, stream>>>(xb, qa);

    attn_kernel<<<dim3(LL / 64, NN * HH), 256, 0, stream>>>(qb, kfb, vfb, ob);

    gemm_o_kernel<<<dim3(HD_ / 128, M_TOT / 128), 256, 0, stream>>>(ob, wot, bo, (float*)d_out);
}

// Round 9
// 315.105 us; speedup vs baseline: 1.2015x; 1.2015x over previous
//
#include <hip/hip_runtime.h>

#define NN 2
#define LL 4096
#define HH 12
#define DD 64
#define HD_ 768
#define M_TOT (NN * LL)   // 8192
#define KVSTRIDE 262144   // elems per (n,h) in pre-permuted K'/V' layouts

typedef __bf16 bf16_t;
typedef _Float16 f16_t;
typedef __bf16 bf16x8 __attribute__((ext_vector_type(8)));
typedef __bf16 bf16x4 __attribute__((ext_vector_type(4)));
typedef _Float16 f16x2 __attribute__((ext_vector_type(2)));
typedef _Float16 f16x4 __attribute__((ext_vector_type(4)));
typedef _Float16 f16x8 __attribute__((ext_vector_type(8)));
typedef float floatx4 __attribute__((ext_vector_type(4)));
typedef float floatx16 __attribute__((ext_vector_type(16)));

// softmax prescale folded into Q at the QKV GEMM: 1/sqrt(64) * log2(e)
#define QSCALE 0.1803368801111f

__device__ __forceinline__ void async_load16(const void* g, void* l) {
    __builtin_amdgcn_global_load_lds(
        (const __attribute__((address_space(1))) unsigned int*)(g),
        (__attribute__((address_space(3))) unsigned int*)(l),
        16, 0, 0);
}

__device__ __forceinline__ f16x2 pkrtz(float a, float b) {
    return __builtin_bit_cast(f16x2, __builtin_amdgcn_cvt_pkrtz(a, b));
}

// ---------------- fp32 -> bf16 convert (x) ---------------------------------
__global__ void cvt_kernel(const float* __restrict__ src, bf16_t* __restrict__ dst, int n4) {
    int i = blockIdx.x * blockDim.x + threadIdx.x;
    if (i < n4) {
        const float4 v = ((const float4*)src)[i];
        bf16_t* d = dst + (size_t)i * 4;
        d[0] = (bf16_t)v.x; d[1] = (bf16_t)v.y; d[2] = (bf16_t)v.z; d[3] = (bf16_t)v.w;
    }
}

// ------------- fp32 W (K x N) -> bf16 W^T (N x K), LDS tile transpose ------
struct WtArgs { const float* W[4]; bf16_t* Wt[4]; };
__global__ __launch_bounds__(256) void cvt_wt_kernel(WtArgs a) {
    __shared__ bf16_t T[64 * 65];
    const int z = blockIdx.z;
    const int k0 = blockIdx.y * 64, n0 = blockIdx.x * 64;
    const int tid = threadIdx.x;
    {
        const int k = tid >> 2;
        const int nc = (tid & 3) * 16;
        const float* src = a.W[z] + (size_t)(k0 + k) * HD_ + n0 + nc;
        for (int i = 0; i < 4; ++i) {
            float4 v = *(const float4*)(src + i * 4);
            T[(nc + i * 4 + 0) * 65 + k] = (bf16_t)v.x;
            T[(nc + i * 4 + 1) * 65 + k] = (bf16_t)v.y;
            T[(nc + i * 4 + 2) * 65 + k] = (bf16_t)v.z;
            T[(nc + i * 4 + 3) * 65 + k] = (bf16_t)v.w;
        }
    }
    __syncthreads();
    {
        const int n = tid >> 2;
        const int kc = (tid & 3) * 16;
        bf16_t* dst = a.Wt[z] + (size_t)(n0 + n) * HD_ + k0 + kc;
        bf16x8 v0, v1;
        for (int j = 0; j < 8; ++j) { v0[j] = T[n * 65 + kc + j]; v1[j] = T[n * 65 + kc + 8 + j]; }
        *(bf16x8*)dst = v0;
        *(bf16x8*)(dst + 8) = v1;
    }
}

// ---------------- m97-style 128x128 GEMM tile core -------------------------
__device__ __forceinline__ void gemm_tile128(
    const bf16_t* __restrict__ A, const bf16_t* __restrict__ Bt,
    bf16_t* As, bf16_t* Bs, int m0, int n0, floatx4 (&acc)[4][4])
{
    const int tid  = threadIdx.x;
    const int w    = tid >> 6, lane = tid & 63;
    const int quad = lane >> 4, l16 = lane & 15;
    const int wm = w >> 1, wn = w & 1;
    const int rsub = lane >> 3;
    const int csub = (lane & 7) * 8;

    const bf16_t* aBase = A + (size_t)(m0 + w * 32 + rsub) * HD_ + csub;
    const bf16_t* bBase = Bt + (size_t)(n0 + w * 32 + rsub) * HD_ + csub;

    for (int kt = 0; kt < HD_; kt += 64) {
        __syncthreads();
        for (int i = 0; i < 4; ++i) {
            const int ar = w * 32 + i * 8;
            async_load16(aBase + (size_t)i * 8 * HD_ + kt, As + ar * 64 + lane * 8);
            async_load16(bBase + (size_t)i * 8 * HD_ + kt, Bs + ar * 64 + lane * 8);
        }
        __syncthreads();
        for (int ks = 0; ks < 2; ++ks) {
            bf16x8 af[4], bf[4];
            for (int mi = 0; mi < 4; ++mi)
                af[mi] = *(const bf16x8*)&As[(wm * 64 + mi * 16 + l16) * 64 + ks * 32 + quad * 8];
            for (int ni = 0; ni < 4; ++ni)
                bf[ni] = *(const bf16x8*)&Bs[(wn * 64 + ni * 16 + l16) * 64 + ks * 32 + quad * 8];
            for (int mi = 0; mi < 4; ++mi)
                for (int ni = 0; ni < 4; ++ni)
                    acc[mi][ni] = __builtin_amdgcn_mfma_f32_16x16x32_bf16(
                        af[mi], bf[ni], acc[mi][ni], 0, 0, 0);
        }
    }
}

// ---------------- fused QKV projection (z = 0:Q, 1:K, 2:V) -----------------
// K' layout: nh | kvb=l>>5 | s=d>>4 | (l&31)+32*((d>>3)&1) | d&7
// V' layout (kv bits 2<->3 swapped so P needs no lane shuffles):
//   nh | (l>>6)*2+(d>>5) | (l>>4)&3 | (d&31)+32*((l>>2)&1) | (l&3)+4*((l>>3)&1)
struct QKVArgs {
    const bf16_t* Bt[3];
    const float* bias[3];
    void* out[3];
};
__global__ __launch_bounds__(256) void gemm_qkv_kernel(const bf16_t* __restrict__ A, QKVArgs p)
{
    __shared__ __align__(16) bf16_t S[2 * 128 * 64];   // As | Bs, reused as out-stage
    const int z = blockIdx.z;
    const int m0 = blockIdx.y * 128, n0 = blockIdx.x * 128;

    floatx4 acc[4][4] = {};
    gemm_tile128(A, p.Bt[z], S, S + 8192, m0, n0, acc);

    const int tid  = threadIdx.x;
    const int lane = tid & 63;
    const int quad = lane >> 4, l16 = lane & 15;
    const int w    = tid >> 6;
    const int wm = w >> 1, wn = w & 1;
    const float scale = (z == 0) ? QSCALE : 1.0f;
    const float* bias = p.bias[z];

    __syncthreads();   // all waves done reading As/Bs
    for (int ni = 0; ni < 4; ++ni) {
        const int dl = ni * 16 + l16;
        const float bv = bias[n0 + wn * 64 + dl];
        for (int mi = 0; mi < 4; ++mi) {
            for (int r = 0; r < 4; ++r) {
                const int ll = wm * 64 + mi * 16 + quad * 4 + r;
                const float val = (acc[mi][ni][r] + bv) * scale;
                int off;
                if (z == 0)
                    off = ll * 64 + dl;
                else if (z == 1)
                    off = ((ll >> 5) * 4 + (dl >> 4)) * 512
                        + ((ll & 31) + 32 * ((dl >> 3) & 1)) * 8 + (dl & 7);
                else
                    off = (((ll >> 6) * 2 + (dl >> 5)) * 4 + ((ll >> 4) & 3)) * 512
                        + ((dl & 31) + 32 * ((ll >> 2) & 1)) * 8
                        + ((ll & 3) + 4 * ((ll >> 3) & 1));
                if (z == 2) ((f16_t*)S)[wn * 8192 + off] = (f16_t)val;
                else        S[wn * 8192 + off] = (bf16_t)val;
            }
        }
    }
    __syncthreads();

    // copy out: 16 KB per head, fully contiguous in global
    const int ht = tid >> 7, idx = tid & 127;
    const int nn = m0 >> 12, l0 = m0 & 4095;
    const int h = (n0 >> 6) + ht;
    char* dstBase;
    if (z == 0)
        dstBase = (char*)p.out[0] + (((size_t)(nn * HH + h) * LL + l0) * 64) * 2;
    else if (z == 1)
        dstBase = (char*)p.out[1] + ((size_t)(nn * HH + h) * KVSTRIDE + (size_t)(l0 >> 5) * 2048) * 2;
    else
        dstBase = (char*)p.out[2] + ((size_t)(nn * HH + h) * KVSTRIDE + (size_t)(l0 >> 6) * 4096) * 2;
    const bf16_t* srcB = S + ht * 8192;
    for (int c = 0; c < 8; ++c) {
        const int cc = (c + idx) & 7;   // bank-rotated: conflict-minimal b128 reads
        *(bf16x8*)(dstBase + (idx * 64 + cc * 8) * 2) = *(const bf16x8*)(srcB + idx * 64 + cc * 8);
    }
}

// ---------------- output projection (fp32 out) -----------------------------
__global__ __launch_bounds__(256) void gemm_o_kernel(
    const bf16_t* __restrict__ A, const bf16_t* __restrict__ Bt,
    const float* __restrict__ bias, float* __restrict__ Cout)
{
    __shared__ __align__(16) bf16_t As[128 * 64];
    __shared__ __align__(16) bf16_t Bs[128 * 64];
    const int m0 = blockIdx.y * 128, n0 = blockIdx.x * 128;

    floatx4 acc[4][4] = {};
    gemm_tile128(A, Bt, As, Bs, m0, n0, acc);

    const int tid  = threadIdx.x;
    const int lane = tid & 63;
    const int quad = lane >> 4, l16 = lane & 15;
    const int w    = tid >> 6;
    const int wm = w >> 1, wn = w & 1;

    for (int ni = 0; ni < 4; ++ni) {
        const int col = n0 + wn * 64 + ni * 16 + l16;
        const float bv = bias[col];
        for (int mi = 0; mi < 4; ++mi)
            for (int r = 0; r < 4; ++r) {
                const int row = m0 + wm * 64 + mi * 16 + quad * 4 + r;
                Cout[(size_t)row * HD_ + col] = acc[mi][ni][r] + bv;
            }
    }
}

// ---------------- flash attention: round-6 staging + no-shuffle P ----------
// q-tile 128, 4 waves, full kv sweep, SINGLE-buffered LDS (two barriers per
// iter — the validated round-6 shape). S^T = K·Q^T (32x32x16 bf16); the V'
// bit-swap makes sacc regs feed the PV B-operand directly (exp2 -> pkrtz ->
// MFMA, zero cross-lane ops — validated in round 7).
__global__ __launch_bounds__(256) void attn_kernel(
    const bf16_t* __restrict__ qg, const bf16_t* __restrict__ kf,
    const f16_t* __restrict__ vf, bf16_t* __restrict__ og)
{
    __shared__ union {
        struct { bf16_t Ks[8 * 512]; f16_t Vs[8 * 512]; } s;  // 8+8 KB
        bf16_t OT[128 * 72];                                  // epilogue (18 KB)
    } u;

    const int tid = threadIdx.x;
    const int w = tid >> 6, lane = tid & 63;
    const int l32 = lane & 31, hi = lane >> 5;
    const int qt0 = blockIdx.x * 128;
    const int nh = blockIdx.y;
    const int nIdx = nh / HH, hIdx = nh % HH;

    // Q B-frags: lane (q=l32, hi) holds Q[qrow][s*16 + hi*8 + j]
    bf16x8 qfrag[4];
    {
        const bf16_t* qp = qg + ((size_t)nh * LL + qt0 + w * 32 + l32) * DD + hi * 8;
        for (int s = 0; s < 4; ++s) qfrag[s] = *(const bf16x8*)(qp + s * 16);
    }

    // DMA: wave w stages chunks {2w, 2w+1} of each 8-chunk (8 KB) tile
    const bf16_t* ksrc = kf + (size_t)nh * KVSTRIDE + (2 * w) * 512 + lane * 8;
    const f16_t*  vsrc = vf + (size_t)nh * KVSTRIDE + (2 * w) * 512 + lane * 8;
    bf16_t* kdst0 = &u.s.Ks[(2 * w) * 512 + lane * 8];
    bf16_t* kdst1 = &u.s.Ks[(2 * w + 1) * 512 + lane * 8];
    f16_t*  vdst0 = &u.s.Vs[(2 * w) * 512 + lane * 8];
    f16_t*  vdst1 = &u.s.Vs[(2 * w + 1) * 512 + lane * 8];

    floatx16 oacc[2] = {};
    float rs = 0.f;

    for (int t = 0; t < 64; ++t) {
        __syncthreads();
        async_load16(ksrc,       kdst0);
        async_load16(ksrc + 512, kdst1);
        async_load16(vsrc,       vdst0);
        async_load16(vsrc + 512, vdst1);
        ksrc += 4096; vsrc += 4096;
        __syncthreads();

        for (int kvb = 0; kvb < 2; ++kvb) {
            floatx16 sacc = {};
            for (int s = 0; s < 4; ++s) {
                bf16x8 ak = *(const bf16x8*)&u.s.Ks[(kvb * 4 + s) * 512 + lane * 8];
                sacc = __builtin_amdgcn_mfma_f32_32x32x16_bf16(ak, qfrag[s], sacc, 0, 0, 0);
            }
            for (int sub = 0; sub < 2; ++sub) {
                float p[8];
                for (int i = 0; i < 8; ++i) {
                    p[i] = __builtin_amdgcn_exp2f(sacc[sub * 8 + i]);
                    rs += p[i];
                }
                f16x2 ab = pkrtz(p[0], p[1]), cd = pkrtz(p[2], p[3]);
                f16x2 ef = pkrtz(p[4], p[5]), gh = pkrtz(p[6], p[7]);
                f16x4 lo4 = __builtin_shufflevector(ab, cd, 0, 1, 2, 3);
                f16x4 hi4 = __builtin_shufflevector(ef, gh, 0, 1, 2, 3);
                f16x8 pf = __builtin_shufflevector(lo4, hi4, 0, 1, 2, 3, 4, 5, 6, 7);
                const int kstep = kvb * 2 + sub;
                for (int db = 0; db < 2; ++db) {
                    f16x8 av = *(const f16x8*)&u.s.Vs[(db * 4 + kstep) * 512 + lane * 8];
                    oacc[db] = __builtin_amdgcn_mfma_f32_32x32x16_f16(av, pf, oacc[db], 0, 0, 0);
                }
            }
        }
    }

    // full row sum per q: add the partner half-wave's partial
    rs += __shfl_xor(rs, 32);
    const float rinv = __builtin_amdgcn_rcpf(rs);

    // O^T -> O via LDS transpose, then coalesced store
    __syncthreads();
    for (int db = 0; db < 2; ++db)
        for (int g = 0; g < 4; ++g) {
            bf16x4 o4;
            for (int r = 0; r < 4; ++r)
                o4[r] = (bf16_t)(oacc[db][g * 4 + r] * rinv);
            // d = r + 8g + 4hi + 32db
            *(bf16x4*)&u.OT[(w * 32 + l32) * 72 + db * 32 + hi * 4 + g * 8] = o4;
        }
    __syncthreads();

    const int q = tid >> 1, hf = tid & 1;
    const bf16_t* src = &u.OT[q * 72 + hf * 32];
    bf16x8 r0 = *(const bf16x8*)(src + 0);
    bf16x8 r1 = *(const bf16x8*)(src + 8);
    bf16x8 r2 = *(const bf16x8*)(src + 16);
    bf16x8 r3 = *(const bf16x8*)(src + 24);
    bf16_t* dst = og + ((size_t)nIdx * LL + qt0 + q) * HD_ + hIdx * 64 + hf * 32;
    *(bf16x8*)(dst + 0)  = r0;
    *(bf16x8*)(dst + 8)  = r1;
    *(bf16x8*)(dst + 16) = r2;
    *(bf16x8*)(dst + 24) = r3;
}

extern "C" void kernel_launch(void* const* d_in, const int* in_sizes, int n_in,
                              void* d_out, int out_size, void* d_ws, size_t ws_size,
                              hipStream_t stream) {
    const float* x  = (const float*)d_in[0];
    const float* Wq = (const float*)d_in[1];
    const float* bq = (const float*)d_in[2];
    const float* Wk = (const float*)d_in[3];
    const float* bk = (const float*)d_in[4];
    const float* Wv = (const float*)d_in[5];
    const float* bv = (const float*)d_in[6];
    const float* Wo = (const float*)d_in[7];
    const float* bo = (const float*)d_in[8];

    char* ws = (char*)d_ws;
    const size_t xbytes = (size_t)M_TOT * HD_ * 2;
    const size_t wbytes = (size_t)HD_ * HD_ * 2;

    bf16_t* xb  = (bf16_t*)ws; ws += xbytes;
    bf16_t* wqt = (bf16_t*)ws; ws += wbytes;
    bf16_t* wkt = (bf16_t*)ws; ws += wbytes;
    bf16_t* wvt = (bf16_t*)ws; ws += wbytes;
    bf16_t* wot = (bf16_t*)ws; ws += wbytes;
    bf16_t* qb  = (bf16_t*)ws; ws += xbytes;
    bf16_t* kfb = (bf16_t*)ws; ws += xbytes;
    f16_t*  vfb = (f16_t*)ws;  ws += xbytes;
    bf16_t* ob  = (bf16_t*)ws; ws += xbytes;

    cvt_kernel<<<(M_TOT * HD_ / 4 + 255) / 256, 256, 0, stream>>>(x, xb, M_TOT * HD_ / 4);

    WtArgs wa;
    wa.W[0] = Wq; wa.W[1] = Wk; wa.W[2] = Wv; wa.W[3] = Wo;
    wa.Wt[0] = wqt; wa.Wt[1] = wkt; wa.Wt[2] = wvt; wa.Wt[3] = wot;
    cvt_wt_kernel<<<dim3(12, 12, 4), 256, 0, stream>>>(wa);

    QKVArgs qa;
    qa.Bt[0] = wqt; qa.Bt[1] = wkt; qa.Bt[2] = wvt;
    qa.bias[0] = bq; qa.bias[1] = bk; qa.bias[2] = bv;
    qa.out[0] = qb; qa.out[1] = kfb; qa.out[2] = vfb;
    gemm_qkv_kernel<<<dim3(HD_ / 128, M_TOT / 128, 3), 256, 0, stream>>>(xb, qa);

    attn_kernel<<<dim3(LL / 128, NN * HH), 256, 0, stream>>>(qb, kfb, vfb, ob);

    gemm_o_kernel<<<dim3(HD_ / 128, M_TOT / 128), 256, 0, stream>>>(ob, wot, bo, (float*)d_out);
}